// Round 3
// baseline (873.005 us; speedup 1.0000x reference)
//
#include <hip/hip_runtime.h>

typedef unsigned short u16;
typedef unsigned int u32;
typedef __bf16 bf16;
typedef __attribute__((ext_vector_type(8))) __bf16 bf16x8;
typedef __attribute__((ext_vector_type(4))) float f32x4;
typedef __attribute__((ext_vector_type(8))) float f32x8;
typedef __attribute__((ext_vector_type(4))) u16 u16x4;

#define NKPT 80
#define LSPIRAL 41

__device__ __forceinline__ float b2f(u16 v) { return __uint_as_float(((u32)v) << 16); }
__device__ __forceinline__ u16 f2b(float f) {
  u32 u = __float_as_uint(f);
  return (u16)((u + 0x7FFFu + ((u >> 16) & 1u)) >> 16);
}

// ---------------------------------------------------------------------------
// Software grid barrier (capture-safe replacement for cooperative grid.sync).
// Co-residency of all gridDim.x blocks is guaranteed by launch config:
// 512 blocks, __launch_bounds__(256,2) -> 2 blocks/CU * 256 CUs, 32KB LDS/blk.
// Agent-scope atomics + __threadfence give cross-XCD visibility (wbl2/inv).
// bar[0] = arrival counter, bar[1] = generation. Zeroed by zero_bar each call.
// ---------------------------------------------------------------------------
__device__ __forceinline__ void gbar(int* bar, int nb) {
  __syncthreads();
  if (threadIdx.x == 0) {
    __threadfence();  // release: write back this block's stores
    const int g = __hip_atomic_load(bar + 1, __ATOMIC_RELAXED, __HIP_MEMORY_SCOPE_AGENT);
    const int v = __hip_atomic_fetch_add(bar, 1, __ATOMIC_ACQ_REL, __HIP_MEMORY_SCOPE_AGENT);
    if (v == nb - 1) {
      __hip_atomic_store(bar, 0, __ATOMIC_RELAXED, __HIP_MEMORY_SCOPE_AGENT);
      __hip_atomic_store(bar + 1, g + 1, __ATOMIC_RELEASE, __HIP_MEMORY_SCOPE_AGENT);
    } else {
      while (__hip_atomic_load(bar + 1, __ATOMIC_RELAXED, __HIP_MEMORY_SCOPE_AGENT) == g)
        __builtin_amdgcn_s_sleep(2);
    }
    __threadfence();  // acquire: invalidate so we see other blocks' stores
  }
  __syncthreads();
}

__global__ void zero_bar(int* bar) {
  if (threadIdx.x < 16) bar[threadIdx.x] = 0;
}

// ---------------------------------------------------------------------------
// Device building blocks (bodies identical to the round-1 verified kernels).
// ---------------------------------------------------------------------------

// Weight f32->bf16 conversion, flat f32x4 index over W1|W2|W3.
#define CVT_TOTAL 1091584
__device__ __forceinline__ void cvt_range(int i, const float* __restrict__ W1,
    const float* __restrict__ W2, const float* __restrict__ W3,
    u16* __restrict__ W1b, u16* __restrict__ W2b, u16* __restrict__ W3b) {
  const float* src; u16* dst; int off;
  if (i < 671744)       { src = W1; dst = W1b; off = 0; }
  else if (i < 1007616) { src = W2; dst = W2b; off = 671744; }
  else                  { src = W3; dst = W3b; off = 1007616; }
  const int j = i - off;
  const f32x4 v = *(const f32x4*)(src + (size_t)j * 4);
  u16x4 o;
#pragma unroll
  for (int t = 0; t < 4; t++) o[t] = f2b(v[t]);
  *(u16x4*)(dst + (size_t)j * 4) = o;
}

// L0 tile: M=128 (batch), BN=64 at bn0, K=1024. A=x fp32 (cvt at load),
// B=W0 fp32 (cvt at load). Out bf16 + bias, no act. N=20480.
__device__ void dev_l0_tile(int bn0, const float* __restrict__ x,
                            const float* __restrict__ W0,
                            const float* __restrict__ b0,
                            u16* __restrict__ Out, u16* As, u16* Bs) {
  const int tid = threadIdx.x, lane = tid & 63, wave = tid >> 6;
  const int rIn = lane >> 3;
  const int koff = ((lane & 7) ^ rIn) * 8;
  const float* aP[4]; u16* aD[4];
  const float* bP[2]; u16* bD[2];
#pragma unroll
  for (int i = 0; i < 4; i++) {
    const int q = i * 4 + wave;
    aP[i] = x + (size_t)(q * 8 + rIn) * 1024 + koff;
    aD[i] = As + q * 512;
  }
#pragma unroll
  for (int i = 0; i < 2; i++) {
    const int q = i * 4 + wave;
    bP[i] = W0 + (size_t)(bn0 + q * 8 + rIn) * 1024 + koff;
    bD[i] = Bs + q * 512;
  }
  f32x4 acc[4][2];
#pragma unroll
  for (int i = 0; i < 4; i++)
#pragma unroll
    for (int j = 0; j < 2; j++) acc[i][j] = (f32x4){0.f, 0.f, 0.f, 0.f};

  const int wm = (wave >> 1) * 64, wn = (wave & 1) * 32;
  const int m15 = lane & 15, quad = lane >> 4;
  const int fko0 = ((0 + quad) ^ (lane & 7)) * 8;
  const int fko1 = ((4 + quad) ^ (lane & 7)) * 8;

  bf16x8 curA[4], nxtA[4], curB[2], nxtB[2];
  auto ldA = [&](int k0, bf16x8* d) {
#pragma unroll
    for (int i = 0; i < 4; i++) {
      const f32x8 v = *(const f32x8*)(aP[i] + k0);
      bf16x8 w;
#pragma unroll
      for (int t = 0; t < 8; t++) w[t] = (bf16)v[t];
      d[i] = w;
    }
  };
  auto ldB = [&](int k0, bf16x8* d) {
#pragma unroll
    for (int i = 0; i < 2; i++) {
      const f32x8 v = *(const f32x8*)(bP[i] + k0);
      bf16x8 w;
#pragma unroll
      for (int t = 0; t < 8; t++) w[t] = (bf16)v[t];
      d[i] = w;
    }
  };
  ldA(0, curA); ldB(0, curB);

  for (int it = 0; it < 16; ++it) {
    __syncthreads();
#pragma unroll
    for (int i = 0; i < 4; i++) *(bf16x8*)(aD[i] + lane * 8) = curA[i];
#pragma unroll
    for (int i = 0; i < 2; i++) *(bf16x8*)(bD[i] + lane * 8) = curB[i];
    __syncthreads();
    const bool more = (it + 1 < 16);
    if (more) { ldA((it + 1) * 64, nxtA); ldB((it + 1) * 64, nxtB); }
#pragma unroll
    for (int kk = 0; kk < 2; kk++) {
      const int fko = kk ? fko1 : fko0;
      bf16x8 av[4], bv[2];
#pragma unroll
      for (int i = 0; i < 4; i++)
        av[i] = *(const bf16x8*)(As + (wm + i * 16 + m15) * 64 + fko);
#pragma unroll
      for (int j = 0; j < 2; j++)
        bv[j] = *(const bf16x8*)(Bs + (wn + j * 16 + m15) * 64 + fko);
#pragma unroll
      for (int i = 0; i < 4; i++)
#pragma unroll
        for (int j = 0; j < 2; j++)
          acc[i][j] = __builtin_amdgcn_mfma_f32_16x16x32_bf16(av[i], bv[j], acc[i][j], 0, 0, 0);
    }
    if (more) {
#pragma unroll
      for (int i = 0; i < 4; i++) curA[i] = nxtA[i];
#pragma unroll
      for (int i = 0; i < 2; i++) curB[i] = nxtB[i];
    }
  }
  // C/D layout: col = lane&15, row = quad*4 + reg
#pragma unroll
  for (int i = 0; i < 4; i++) {
    const int r = wm + i * 16 + quad * 4;
#pragma unroll
    for (int j = 0; j < 2; j++) {
      const int c = bn0 + wn + j * 16 + m15;
      const float bv = b0[c];
#pragma unroll
      for (int t = 0; t < 4; t++)
        Out[(size_t)(r + t) * 20480 + c] = f2b(acc[i][j][t] + bv);
    }
  }
}

// Grouped-GEMM tile for one (grp, bn0): 128 batches x 128 cols x K=C.
// B cols are [U|V|S|T] slices of W (chunk starting at o0, width Oc=1<<lg).
__device__ void dev_grp_tile(int grp, int bn0, const u16* __restrict__ A,
    const u16* __restrict__ Wb, float* __restrict__ P2,
    int C, int ldw, int o0, int lgOc, int NC, u16* As, u16* Bs) {
  const int tid = threadIdx.x, lane = tid & 63, wave = tid >> 6;
  const int jj = grp < 40 ? grp : grp - 40;
  const int OcM = (1 << lgOc) - 1;
  const int rIn = lane >> 3;
  const int koff = ((lane & 7) ^ rIn) * 8;

  const u16 *aPtr[4], *bPtr[4];
  u16 *aDst[4], *bDst[4];
#pragma unroll
  for (int i = 0; i < 4; i++) {
    const int q = i * 4 + wave;
    const int rb = q * 8 + rIn;
    aPtr[i] = A + ((size_t)rb * 80 + grp) * C + koff;
    aDst[i] = As + q * 512;
    const int oc = bn0 + q * 8 + rIn;
    const int part = oc >> lgOc;
    const int orow = o0 + (oc & OcM);
    const int poff = part == 0 ? (jj + 1) * C
                   : part == 1 ? jj * C
                   : part == 2 ? 0
                               : 40 * C;
    bPtr[i] = Wb + (size_t)orow * ldw + poff + koff;
    bDst[i] = Bs + q * 512;
  }

  f32x4 acc[4][4];
#pragma unroll
  for (int i = 0; i < 4; i++)
#pragma unroll
    for (int jn = 0; jn < 4; jn++) acc[i][jn] = (f32x4){0.f, 0.f, 0.f, 0.f};

  const int wm = (wave >> 1) * 64, wn = (wave & 1) * 64;
  const int m15 = lane & 15, quad = lane >> 4;
  const int fko0 = ((0 + quad) ^ (lane & 7)) * 8;
  const int fko1 = ((4 + quad) ^ (lane & 7)) * 8;
  const int iters = C >> 6;  // 4 (C=256) or 2 (C=128)

  bf16x8 curA[4], nxtA[4], curB[4], nxtB[4];
#pragma unroll
  for (int i = 0; i < 4; i++) {
    curA[i] = *(const bf16x8*)(aPtr[i]);
    curB[i] = *(const bf16x8*)(bPtr[i]);
  }

  for (int it = 0; it < iters; ++it) {
    __syncthreads();
#pragma unroll
    for (int i = 0; i < 4; i++) {
      *(bf16x8*)(aDst[i] + lane * 8) = curA[i];
      *(bf16x8*)(bDst[i] + lane * 8) = curB[i];
    }
    __syncthreads();
    const bool more = (it + 1 < iters);
    if (more) {
      const int k0 = (it + 1) * 64;
#pragma unroll
      for (int i = 0; i < 4; i++) {
        nxtA[i] = *(const bf16x8*)(aPtr[i] + k0);
        nxtB[i] = *(const bf16x8*)(bPtr[i] + k0);
      }
    }
#pragma unroll
    for (int kk = 0; kk < 2; kk++) {
      const int fko = kk ? fko1 : fko0;
      bf16x8 av[4], bv[4];
#pragma unroll
      for (int i = 0; i < 4; i++)
        av[i] = *(const bf16x8*)(As + (wm + i * 16 + m15) * 64 + fko);
#pragma unroll
      for (int jn = 0; jn < 4; jn++)
        bv[jn] = *(const bf16x8*)(Bs + (wn + jn * 16 + m15) * 64 + fko);
#pragma unroll
      for (int i = 0; i < 4; i++)
#pragma unroll
        for (int jn = 0; jn < 4; jn++)
          acc[i][jn] = __builtin_amdgcn_mfma_f32_16x16x32_bf16(av[i], bv[jn], acc[i][jn], 0, 0, 0);
    }
    if (more) {
#pragma unroll
      for (int i = 0; i < 4; i++) { curA[i] = nxtA[i]; curB[i] = nxtB[i]; }
    }
  }

  // C/D layout: col = lane&15, row(batch) = quad*4 + reg
#pragma unroll
  for (int i = 0; i < 4; i++) {
    const int rb0 = wm + i * 16 + quad * 4;
#pragma unroll
    for (int jn = 0; jn < 4; jn++) {
      const int c = bn0 + wn + jn * 16 + m15;
#pragma unroll
      for (int t = 0; t < 4; t++)
        P2[((size_t)(rb0 + t) * 80 + grp) * NC + c] = acc[i][jn][t];
    }
  }
}

// Combine one (b, f, oc): prefix-U / suffix-V scan + S + T(partner) + bias,
// ELU, bf16 store of all 40 node outputs.
__device__ void dev_combine(int t, const float* __restrict__ P2,
    const float* __restrict__ bias, u16* __restrict__ Hout,
    int lgOc, int o0, int Ofull, int NC) {
  const int Oc = 1 << lgOc;
  const int oc = t & (Oc - 1);
  const int f = (t >> lgOc) & 1;
  const int b = t >> (lgOc + 1);

  const int rowbase = b * 80 + f * 40;
  const float* Pbase = P2 + (size_t)rowbase * NC + oc;   // U
  const float* Vbase = Pbase + Oc;                       // V
  const float* Sbase = Pbase + 2 * Oc;                   // S
  const float* Tbase = P2 + (size_t)(b * 80 + (1 - f) * 40) * NC + 3 * Oc + oc;
  u16* outp = Hout + (size_t)rowbase * Ofull + o0 + oc;

  float pv[40];
  float totV = 0.f;
#pragma unroll
  for (int j = 0; j < 40; j++) {
    pv[j] = Vbase[j * NC];
    totV += pv[j];
  }
  const float bval = bias[o0 + oc];
  float pre = 0.f, vle = 0.f;
#pragma unroll
  for (int nn = 0; nn < 40; nn++) {
    vle += pv[nn];
    float val = pre + (totV - vle) + Sbase[nn * NC] + Tbase[nn * NC] + bval;
    val = val > 0.f ? val : (__expf(val) - 1.f);
    outp[nn * Ofull] = f2b(val);
    pre += Pbase[nn * NC];
  }
}

// Final projection row r (one wave per r).
__device__ void dev_final(int r, const u16* __restrict__ h3,
    const float* __restrict__ W4, const float* __restrict__ b4,
    const int* __restrict__ gidx, float* __restrict__ out) {
  const int lane = threadIdx.x & 63;
  const int b = r / 80;
  const int n = r - b * 80;
  const int* ip = gidx + n * LSPIRAL;
  const float* w0 = W4 + lane;
  const float* w1 = W4 + 2624 + lane;
  const u16* hb = h3 + b * (NKPT * 64) + lane;
  float a0 = 0.f, a1 = 0.f;
  for (int l = 0; l < LSPIRAL; l++) {
    int J = ip[l];
    J = min(max(J, 0), NKPT - 1);
    const float hv = b2f(hb[J * 64]);
    a0 += hv * w0[l * 64];
    a1 += hv * w1[l * 64];
  }
#pragma unroll
  for (int off = 32; off > 0; off >>= 1) {
    a0 += __shfl_down(a0, off, 64);
    a1 += __shfl_down(a1, off, 64);
  }
  if (lane == 0) {
    out[r * 2 + 0] = a0 + b4[0];
    out[r * 2 + 1] = a1 + b4[1];
  }
}

// ---------------------------------------------------------------------------
// Persistent mega-kernel: whole network in ONE launch, software grid barrier.
// ---------------------------------------------------------------------------
struct MegaP {
  const float *x, *W0, *b0, *W1, *b1, *W2, *b2, *W3, *b3, *W4, *b4;
  const int* idx;
  float* out;
  u16 *hA, *hB, *W1b, *W2b, *W3b;
  float* P2;
  int* bar;
  int lg1, lg2, lg3;
};

__device__ void layer_run(int* bar, const u16* hin, const u16* Wb,
                          const float* bias, u16* hout, int C, int ldw, int O,
                          int lg, float* P2, u16* As, u16* Bs,
                          int nb, int bid, int tid) {
  const int NC = 4 << lg;
  const int NT = NC >> 7;  // NC/128 (>=1 since lg>=5)
  const int Oc = 1 << lg;
  for (int o0 = 0; o0 < O; o0 += Oc) {
    for (int tile = bid; tile < 80 * NT; tile += nb)
      dev_grp_tile(tile % 80, (tile / 80) * 128, hin, Wb, P2, C, ldw, o0, lg, NC, As, Bs);
    gbar(bar, nb);
    const int tot = 256 << lg;  // 128*2*Oc
    for (int t = bid * 256 + tid; t < tot; t += nb * 256)
      dev_combine(t, P2, bias, hout, lg, o0, O, NC);
    gbar(bar, nb);
  }
}

__global__ __launch_bounds__(256, 2)
void mega(MegaP p) {
  __shared__ u16 As[8192];
  __shared__ u16 Bs[8192];
  const int nb = gridDim.x, bid = blockIdx.x, tid = threadIdx.x;

  // Phase 1: weight cvt (all blocks) + L0 tiles (first 320 blocks).
  // L0 reads x/W0 fp32 directly, so no dependency on the cvt outputs.
  for (int i = bid * 256 + tid; i < CVT_TOTAL; i += nb * 256)
    cvt_range(i, p.W1, p.W2, p.W3, p.W1b, p.W2b, p.W3b);
  for (int t0 = bid; t0 < 320; t0 += nb)
    dev_l0_tile(t0 * 64, p.x, p.W0, p.b0, p.hA, As, Bs);
  gbar(p.bar, nb);

  layer_run(p.bar, p.hA, p.W1b, p.b1, p.hB, 256, 10496, 256, p.lg1, p.P2, As, Bs, nb, bid, tid);
  layer_run(p.bar, p.hB, p.W2b, p.b2, p.hA, 256, 10496, 128, p.lg2, p.P2, As, Bs, nb, bid, tid);
  layer_run(p.bar, p.hA, p.W3b, p.b3, p.hB, 128, 5248, 64, p.lg3, p.P2, As, Bs, nb, bid, tid);

  for (int vb = bid; vb < 2560; vb += nb)
    dev_final(vb * 4 + (tid >> 6), p.hB, p.W4, p.b4, p.idx, p.out);
}

// ---------------------------------------------------------------------------
// Small-workspace fallback path (round-0 proven gather-GEMM chain).
// ---------------------------------------------------------------------------
__global__ __launch_bounds__(256)
void cvt_x(const float* __restrict__ x, u16* __restrict__ xb) {
  const int i = blockIdx.x * 256 + threadIdx.x;
  if (i < 32768) {
    const f32x4 v = *(const f32x4*)(x + (size_t)i * 4);
    u16x4 o;
#pragma unroll
    for (int t = 0; t < 4; t++) o[t] = f2b(v[t]);
    *(u16x4*)(xb + (size_t)i * 4) = o;
  }
}

__global__ __launch_bounds__(256)
void final_k(const u16* __restrict__ h3, const float* __restrict__ W4,
             const float* __restrict__ b4, const int* __restrict__ gidx,
             float* __restrict__ out) {
  dev_final(blockIdx.x * 4 + (threadIdx.x >> 6), h3, W4, b4, gidx, out);
}

template <int BM, int BN, int GATHER, int LOG2C, int OUTM, int BCVT, int LW>
__global__ __launch_bounds__(256)
void gemm_sp(const u16* __restrict__ A, const void* __restrict__ Wt,
             const int* __restrict__ gidx, float* __restrict__ P,
             u16* __restrict__ Out, const float* __restrict__ bias, int act,
             int N, int K, int itersTotal, int itersPerSplit) {
  constexpr int BK = 64;
  constexpr int WN = BN / 2;
  constexpr int TN = WN / 16;
  constexpr int IA = BM / 32;
  constexpr int IB = BN / 32;
  constexpr int CMASK = (1 << LOG2C) - 1;

  __shared__ u16 As[BM * BK];
  __shared__ u16 Bs[BN * BK];
  __shared__ int idx_s[GATHER ? NKPT * LW : 1];

  const int tid = threadIdx.x;
  const int lane = tid & 63;
  const int wave = tid >> 6;

  const int bm0 = blockIdx.x * BM;
  const int bn0 = blockIdx.y * BN;
  const int split = blockIdx.z;
  const int it0 = split * itersPerSplit;
  const int itEnd = min(itersTotal, it0 + itersPerSplit);
  const int l0 = GATHER ? ((it0 * BK) >> LOG2C) : 0;

  if (GATHER) {
    for (int t = tid; t < NKPT * LW; t += 256) {
      const int n = t / LW;
      const int w = t - n * LW;
      idx_s[t] = gidx[n * LSPIRAL + min(l0 + w, LSPIRAL - 1)];
    }
  }

  const int rIn = lane >> 3;
  const int koff = ((lane & 7) ^ rIn) * 8;

  int aBase[IA];
  const int* aIdxP[IA];
  const u16* aPtr[IA];
  u16* aDst[IA];
#pragma unroll
  for (int i = 0; i < IA; i++) {
    const int q = i * 4 + wave;
    const int r = bm0 + q * 8 + rIn;
    aDst[i] = As + q * 512;
    if (GATHER) {
      const int b = (r * 52429) >> 22;
      const int n = r - b * 80;
      aBase[i] = (b * NKPT) << LOG2C;
      aIdxP[i] = idx_s + n * LW;
    } else {
      aPtr[i] = A + (size_t)r * K + koff;
    }
  }
  const u16* bPtrH[IB];
  const float* bPtrF[IB];
  u16* bDst[IB];
#pragma unroll
  for (int i = 0; i < IB; i++) {
    const int q = i * 4 + wave;
    const int o = bn0 + q * 8 + rIn;
    bDst[i] = Bs + q * 512;
    if (BCVT) bPtrF[i] = (const float*)Wt + (size_t)o * K + koff;
    else bPtrH[i] = (const u16*)Wt + (size_t)o * K + koff;
  }

  f32x4 acc[4][TN];
#pragma unroll
  for (int i = 0; i < 4; i++)
#pragma unroll
    for (int j = 0; j < TN; j++) acc[i][j] = (f32x4){0.f, 0.f, 0.f, 0.f};

  const int wm = (wave >> 1) * 64;
  const int wn = (wave & 1) * WN;
  const int m15 = lane & 15;
  const int quad = lane >> 4;
  const int fko0 = ((0 + quad) ^ (lane & 7)) * 8;
  const int fko1 = ((4 + quad) ^ (lane & 7)) * 8;

  if (GATHER) __syncthreads();

  bf16x8 curA[IA], nxtA[IA];
  bf16x8 curB[IB], nxtB[IB];
  f32x8 curBF[BCVT ? IB : 1], nxtBF[BCVT ? IB : 1];

  auto loadA = [&](int it, bf16x8* dst) {
    const int k0 = it * BK;
    if (GATHER) {
      const int dl = (k0 >> LOG2C) - l0;
      const int cb = (k0 & CMASK) + koff;
#pragma unroll
      for (int i = 0; i < IA; i++) {
        int J = aIdxP[i][dl];
        J = min(max(J, 0), NKPT - 1);
        dst[i] = *(const bf16x8*)(A + aBase[i] + (J << LOG2C) + cb);
      }
    } else {
#pragma unroll
      for (int i = 0; i < IA; i++) dst[i] = *(const bf16x8*)(aPtr[i] + k0);
    }
  };
  auto loadBH = [&](int it, bf16x8* dst) {
    const int k0 = it * BK;
#pragma unroll
    for (int i = 0; i < IB; i++) dst[i] = *(const bf16x8*)(bPtrH[i] + k0);
  };
  auto loadBF = [&](int it, f32x8* dst) {
    const int k0 = it * BK;
#pragma unroll
    for (int i = 0; i < IB; i++) dst[i] = *(const f32x8*)(bPtrF[i] + k0);
  };

  loadA(it0, curA);
  if (BCVT) loadBF(it0, curBF); else loadBH(it0, curB);

  for (int it = it0; it < itEnd; ++it) {
    __syncthreads();
#pragma unroll
    for (int i = 0; i < IA; i++) *(bf16x8*)(aDst[i] + lane * 8) = curA[i];
    if (BCVT) {
#pragma unroll
      for (int i = 0; i < IB; i++) {
        bf16x8 w;
#pragma unroll
        for (int t = 0; t < 8; t++) w[t] = (bf16)curBF[i][t];
        *(bf16x8*)(bDst[i] + lane * 8) = w;
      }
    } else {
#pragma unroll
      for (int i = 0; i < IB; i++) *(bf16x8*)(bDst[i] + lane * 8) = curB[i];
    }
    __syncthreads();
    const bool more = (it + 1 < itEnd);
    if (more) {
      loadA(it + 1, nxtA);
      if (BCVT) loadBF(it + 1, nxtBF); else loadBH(it + 1, nxtB);
    }
#pragma unroll
    for (int kk = 0; kk < 2; kk++) {
      const int fko = kk ? fko1 : fko0;
      bf16x8 av[4], bv[TN];
#pragma unroll
      for (int i = 0; i < 4; i++)
        av[i] = *(const bf16x8*)(As + (wm + i * 16 + m15) * BK + fko);
#pragma unroll
      for (int j = 0; j < TN; j++)
        bv[j] = *(const bf16x8*)(Bs + (wn + j * 16 + m15) * BK + fko);
#pragma unroll
      for (int i = 0; i < 4; i++)
#pragma unroll
        for (int j = 0; j < TN; j++)
          acc[i][j] = __builtin_amdgcn_mfma_f32_16x16x32_bf16(av[i], bv[j], acc[i][j], 0, 0, 0);
    }
    if (more) {
#pragma unroll
      for (int i = 0; i < IA; i++) curA[i] = nxtA[i];
      if (BCVT) {
#pragma unroll
        for (int i = 0; i < IB; i++) curBF[i] = nxtBF[i];
      } else {
#pragma unroll
        for (int i = 0; i < IB; i++) curB[i] = nxtB[i];
      }
    }
  }

#pragma unroll
  for (int i = 0; i < 4; i++) {
    const int r = bm0 + wm + i * 16 + quad * 4;
#pragma unroll
    for (int j = 0; j < TN; j++) {
      const int c = bn0 + wn + j * 16 + m15;
      if (OUTM == 0) {
        const float bv = bias[c];
#pragma unroll
        for (int t = 0; t < 4; t++) {
          float v = acc[i][j][t] + bv;
          if (act) v = v > 0.f ? v : (__expf(v) - 1.f);
          Out[(size_t)(r + t) * N + c] = f2b(v);
        }
      } else {
#pragma unroll
        for (int t = 0; t < 4; t++)
          atomicAdd(P + (size_t)(r + t) * N + c, acc[i][j][t]);
      }
    }
  }
}

// ---------------------------------------------------------------------------
extern "C" void kernel_launch(void* const* d_in, const int* in_sizes, int n_in,
                              void* d_out, int out_size, void* d_ws, size_t ws_size,
                              hipStream_t stream) {
  const float* x  = (const float*)d_in[0];
  const float* W0 = (const float*)d_in[1];
  const float* b0 = (const float*)d_in[2];
  const float* W1 = (const float*)d_in[3];
  const float* b1 = (const float*)d_in[4];
  const float* W2 = (const float*)d_in[5];
  const float* b2 = (const float*)d_in[6];
  const float* W3 = (const float*)d_in[7];
  const float* b3 = (const float*)d_in[8];
  const float* W4 = (const float*)d_in[9];
  const float* b4 = (const float*)d_in[10];
  const int* idx = (const int*)d_in[11];
  float* out = (float*)d_out;

  char* ws = (char*)d_ws;
  u16* hA  = (u16*)(ws);                  // 5,242,880
  u16* hB  = (u16*)(ws + 5242880);        // 5,242,880
  u16* W1b = (u16*)(ws + 10485760);       // 5,373,952
  u16* W2b = (u16*)(ws + 15859712);       // 2,686,976
  u16* W3b = (u16*)(ws + 18546688);       //   671,744 -> ends 19,218,432
  int* bar = (int*)(ws + 19218432);       //        64
  float* P2 = (float*)(ws + 19218496);

  const size_t P2cap = ws_size > (size_t)19218496 ? ws_size - 19218496 : 0;

  // P2 bytes for chunk width (1<<lg): 10240 rows * (4<<lg) cols * 4 B
  auto lgFor = [&](int O) {
    int lg = 5;
    while ((1 << (lg + 1)) <= O && (((size_t)163840) << (lg + 1)) <= P2cap) lg++;
    return lg;
  };

  if (P2cap >= (((size_t)163840) << 5)) {  // >= 5,242,880: full path
    MegaP p;
    p.x = x; p.W0 = W0; p.b0 = b0; p.W1 = W1; p.b1 = b1; p.W2 = W2; p.b2 = b2;
    p.W3 = W3; p.b3 = b3; p.W4 = W4; p.b4 = b4; p.idx = idx; p.out = out;
    p.hA = hA; p.hB = hB; p.W1b = W1b; p.W2b = W2b; p.W3b = W3b; p.P2 = P2;
    p.bar = bar;
    p.lg1 = lgFor(256); p.lg2 = lgFor(128); p.lg3 = lgFor(64);

    zero_bar<<<1, 64, 0, stream>>>(bar);
    mega<<<512, 256, 0, stream>>>(p);
  } else {
    // Small-ws fallback: gather-GEMM chain (round-0 proven), xb aliased to hB.
    u16* xb = hB;
    cvt_x<<<128, 256, 0, stream>>>(x, xb);
    gemm_sp<128, 64, 0, 0, 0, 1, 1><<<dim3(1, 320, 1), 256, 0, stream>>>(
        xb, W0, idx, nullptr, hA, b0, 0, 20480, 1024, 16, 16);
    gemm_sp<128, 128, 1, 8, 0, 1, 44><<<dim3(80, 2, 1), 256, 0, stream>>>(
        hA, W1, idx, nullptr, hB, b1, 1, 256, 10496, 164, 164);
    gemm_sp<128, 128, 1, 8, 0, 1, 44><<<dim3(80, 1, 1), 256, 0, stream>>>(
        hB, W2, idx, nullptr, hA, b2, 1, 128, 10496, 164, 164);
    gemm_sp<128, 64, 1, 7, 0, 1, 44><<<dim3(80, 1, 1), 256, 0, stream>>>(
        hA, W3, idx, nullptr, hB, b3, 1, 64, 5248, 82, 82);
    final_k<<<2560, 256, 0, stream>>>(hB, W4, b4, idx, out);
  }
}

// Round 4
// 348.685 us; speedup vs baseline: 2.5037x; 2.5037x over previous
//
#include <hip/hip_runtime.h>

typedef unsigned short u16;
typedef unsigned int u32;
typedef __bf16 bf16;
typedef __attribute__((ext_vector_type(8))) __bf16 bf16x8;
typedef __attribute__((ext_vector_type(4))) float f32x4;
typedef __attribute__((ext_vector_type(8))) float f32x8;
typedef __attribute__((ext_vector_type(4))) u16 u16x4;

#define NKPT 80
#define LSPIRAL 41

__device__ __forceinline__ float b2f(u16 v) { return __uint_as_float(((u32)v) << 16); }
__device__ __forceinline__ u16 f2b(float f) {
  u32 u = __float_as_uint(f);
  return (u16)((u + 0x7FFFu + ((u >> 16) & 1u)) >> 16);
}

// ---------------------------------------------------------------------------
// Weight f32->bf16 conversion, flat f32x4 index over W1|W2|W3.
// ---------------------------------------------------------------------------
#define CVT_TOTAL 1091584
__device__ __forceinline__ void cvt_range(int i, const float* __restrict__ W1,
    const float* __restrict__ W2, const float* __restrict__ W3,
    u16* __restrict__ W1b, u16* __restrict__ W2b, u16* __restrict__ W3b) {
  const float* src; u16* dst; int off;
  if (i < 671744)       { src = W1; dst = W1b; off = 0; }
  else if (i < 1007616) { src = W2; dst = W2b; off = 671744; }
  else                  { src = W3; dst = W3b; off = 1007616; }
  const int j = i - off;
  const f32x4 v = *(const f32x4*)(src + (size_t)j * 4);
  u16x4 o;
#pragma unroll
  for (int t = 0; t < 4; t++) o[t] = f2b(v[t]);
  *(u16x4*)(dst + (size_t)j * 4) = o;
}

// ---------------------------------------------------------------------------
// L0 tile (verified round-1 body): M=128, BN=64 at bn0, K=1024, fp32 in,
// bf16 out + bias, no act. N=20480.
// ---------------------------------------------------------------------------
__device__ void dev_l0_tile(int bn0, const float* __restrict__ x,
                            const float* __restrict__ W0,
                            const float* __restrict__ b0,
                            u16* __restrict__ Out, u16* As, u16* Bs) {
  const int tid = threadIdx.x, lane = tid & 63, wave = tid >> 6;
  const int rIn = lane >> 3;
  const int koff = ((lane & 7) ^ rIn) * 8;
  const float* aP[4]; u16* aD[4];
  const float* bP[2]; u16* bD[2];
#pragma unroll
  for (int i = 0; i < 4; i++) {
    const int q = i * 4 + wave;
    aP[i] = x + (size_t)(q * 8 + rIn) * 1024 + koff;
    aD[i] = As + q * 512;
  }
#pragma unroll
  for (int i = 0; i < 2; i++) {
    const int q = i * 4 + wave;
    bP[i] = W0 + (size_t)(bn0 + q * 8 + rIn) * 1024 + koff;
    bD[i] = Bs + q * 512;
  }
  f32x4 acc[4][2];
#pragma unroll
  for (int i = 0; i < 4; i++)
#pragma unroll
    for (int j = 0; j < 2; j++) acc[i][j] = (f32x4){0.f, 0.f, 0.f, 0.f};

  const int wm = (wave >> 1) * 64, wn = (wave & 1) * 32;
  const int m15 = lane & 15, quad = lane >> 4;
  const int fko0 = ((0 + quad) ^ (lane & 7)) * 8;
  const int fko1 = ((4 + quad) ^ (lane & 7)) * 8;

  bf16x8 curA[4], nxtA[4], curB[2], nxtB[2];
  auto ldA = [&](int k0, bf16x8* d) {
#pragma unroll
    for (int i = 0; i < 4; i++) {
      const f32x8 v = *(const f32x8*)(aP[i] + k0);
      bf16x8 w;
#pragma unroll
      for (int t = 0; t < 8; t++) w[t] = (bf16)v[t];
      d[i] = w;
    }
  };
  auto ldB = [&](int k0, bf16x8* d) {
#pragma unroll
    for (int i = 0; i < 2; i++) {
      const f32x8 v = *(const f32x8*)(bP[i] + k0);
      bf16x8 w;
#pragma unroll
      for (int t = 0; t < 8; t++) w[t] = (bf16)v[t];
      d[i] = w;
    }
  };
  ldA(0, curA); ldB(0, curB);

  for (int it = 0; it < 16; ++it) {
    __syncthreads();
#pragma unroll
    for (int i = 0; i < 4; i++) *(bf16x8*)(aD[i] + lane * 8) = curA[i];
#pragma unroll
    for (int i = 0; i < 2; i++) *(bf16x8*)(bD[i] + lane * 8) = curB[i];
    __syncthreads();
    const bool more = (it + 1 < 16);
    if (more) { ldA((it + 1) * 64, nxtA); ldB((it + 1) * 64, nxtB); }
#pragma unroll
    for (int kk = 0; kk < 2; kk++) {
      const int fko = kk ? fko1 : fko0;
      bf16x8 av[4], bv[2];
#pragma unroll
      for (int i = 0; i < 4; i++)
        av[i] = *(const bf16x8*)(As + (wm + i * 16 + m15) * 64 + fko);
#pragma unroll
      for (int j = 0; j < 2; j++)
        bv[j] = *(const bf16x8*)(Bs + (wn + j * 16 + m15) * 64 + fko);
#pragma unroll
      for (int i = 0; i < 4; i++)
#pragma unroll
        for (int j = 0; j < 2; j++)
          acc[i][j] = __builtin_amdgcn_mfma_f32_16x16x32_bf16(av[i], bv[j], acc[i][j], 0, 0, 0);
    }
    if (more) {
#pragma unroll
      for (int i = 0; i < 4; i++) curA[i] = nxtA[i];
#pragma unroll
      for (int i = 0; i < 2; i++) curB[i] = nxtB[i];
    }
  }
#pragma unroll
  for (int i = 0; i < 4; i++) {
    const int r = wm + i * 16 + quad * 4;
#pragma unroll
    for (int j = 0; j < 2; j++) {
      const int c = bn0 + wn + j * 16 + m15;
      const float bv = b0[c];
#pragma unroll
      for (int t = 0; t < 4; t++)
        Out[(size_t)(r + t) * 20480 + c] = f2b(acc[i][j][t] + bv);
    }
  }
}

// Fused dispatch 1: blocks 0..319 do L0 tiles; blocks 320..447 do weight cvt.
__global__ __launch_bounds__(256)
void fuse0(const float* __restrict__ x, const float* __restrict__ W0,
           const float* __restrict__ b0, const float* __restrict__ W1,
           const float* __restrict__ W2, const float* __restrict__ W3,
           u16* __restrict__ h0, u16* __restrict__ W1b,
           u16* __restrict__ W2b, u16* __restrict__ W3b) {
  const int bid = blockIdx.x;
  if (bid < 320) {
    __shared__ u16 As[8192];
    __shared__ u16 Bs[8192];
    dev_l0_tile(bid * 64, x, W0, b0, h0, As, Bs);
  } else {
    for (int i = (bid - 320) * 256 + threadIdx.x; i < CVT_TOTAL; i += 128 * 256)
      cvt_range(i, W1, W2, W3, W1b, W2b, W3b);
  }
}

// ---------------------------------------------------------------------------
// Fused spiral layer, NO cross-block dependency (no P2, no combine kernel).
// Block = (b-chunk of 16, frame f, o-chunk of 16). Wave w owns nodes
// [10w, 10w+10) of frame f. Per node n (frame-local):
//   out_n = Sum_{j<n} U_j h_j + Sum_{j>n} V_j h_j + S h_n + T h_partner(n)
// with U_j = W[:, (j+1)C], V_j = W[:, jC], S = W[:, 0], T = W[:, 40C].
// Pass A: per-wave tile totals totU, totV. LDS exchange -> prefix/suffix
// bases per wave. Pass B: recompute per-node projections, finish scan, ELU,
// store bf16. All operand fragments loaded direct from global (L2-resident).
// Fragment layout (16x16x32): operand row = lane&15, k = quad*8 + ks*32;
// C/D: col(o) = lane&15, row(b) = quad*4 + reg (m89/m91 verified).
// ---------------------------------------------------------------------------
template <int C, int LDW>
__global__ __launch_bounds__(256)
void layer_f(const u16* __restrict__ hin, const u16* __restrict__ Wb,
             const float* __restrict__ bias, u16* __restrict__ hout,
             int nOC, int O) {
  constexpr int KS = C / 32;
  // bid = b8*(2*nOC) + f*nOC + oc  -> blocks sharing (f,oc) differ by
  // multiples of 2*nOC (>=8), so they share bid%8 -> same XCD class.
  const int bid = blockIdx.x;
  const int b8 = bid / (2 * nOC);
  const int rest = bid - b8 * (2 * nOC);
  const int f = rest / nOC;
  const int oc = rest - f * nOC;
  const int b0 = b8 * 16;
  const int o0 = oc * 16;

  const int tid = threadIdx.x;
  const int lane = tid & 63;
  const int wave = tid >> 6;
  const int m15 = lane & 15;
  const int quad = lane >> 4;

  __shared__ float xch[2048];  // [wave][lane][8]: totU 0..3, totV 4..7

  const u16* hbase = hin + (size_t)(b0 + m15) * (80 * C) + quad * 8;
  const u16* wbase = Wb + (size_t)(o0 + m15) * LDW + quad * 8;

  const int g0 = f * 40;        // this frame's global node offset
  const int gp0 = (1 - f) * 40; // partner frame offset
  const int n0 = wave * 10;

  f32x4 totU = (f32x4){0.f, 0.f, 0.f, 0.f};
  f32x4 totV = (f32x4){0.f, 0.f, 0.f, 0.f};

  // ---- Pass A: per-wave totals ----
  for (int n = n0; n < n0 + 10; ++n) {
    const u16* ha = hbase + (g0 + n) * C;
    const u16* wu = wbase + (n + 1) * C;
    const u16* wv = wbase + n * C;
    f32x4 aU = (f32x4){0.f, 0.f, 0.f, 0.f};
    f32x4 aV = (f32x4){0.f, 0.f, 0.f, 0.f};
#pragma unroll
    for (int ks = 0; ks < KS; ++ks) {
      const bf16x8 av = *(const bf16x8*)(ha + ks * 32);
      const bf16x8 bu = *(const bf16x8*)(wu + ks * 32);
      const bf16x8 bv = *(const bf16x8*)(wv + ks * 32);
      aU = __builtin_amdgcn_mfma_f32_16x16x32_bf16(av, bu, aU, 0, 0, 0);
      aV = __builtin_amdgcn_mfma_f32_16x16x32_bf16(av, bv, aV, 0, 0, 0);
    }
    totU += aU; totV += aV;
  }

  // ---- Exchange: prefix-U / suffix-V bases across waves ----
  {
    float* p = xch + wave * 512 + lane * 8;
#pragma unroll
    for (int t = 0; t < 4; t++) { p[t] = totU[t]; p[4 + t] = totV[t]; }
  }
  __syncthreads();
  f32x4 preU = (f32x4){0.f, 0.f, 0.f, 0.f};
  f32x4 sufV = (f32x4){0.f, 0.f, 0.f, 0.f};
#pragma unroll
  for (int w = 0; w < 4; ++w) {
    const float* p = xch + w * 512 + lane * 8;
    if (w < wave) {
#pragma unroll
      for (int t = 0; t < 4; t++) preU[t] += p[t];
    } else if (w > wave) {
#pragma unroll
      for (int t = 0; t < 4; t++) sufV[t] += p[4 + t];
    }
  }

  // ---- Pass B: per-node finish ----
  // Preload S (slice 0) and T (slice 40) weight fragments (node-invariant).
  bf16x8 wsr[KS], wtr[KS];
#pragma unroll
  for (int ks = 0; ks < KS; ++ks) {
    wsr[ks] = *(const bf16x8*)(wbase + ks * 32);
    wtr[ks] = *(const bf16x8*)(wbase + 40 * C + ks * 32);
  }

  const float bval = bias[o0 + m15];
  f32x4 runU = preU;          // Sum of U_j for j < current n (global)
  f32x4 sufRun = sufV + totV; // Sum of V_j for j >= first node of this wave

  for (int n = n0; n < n0 + 10; ++n) {
    const u16* ha = hbase + (g0 + n) * C;
    const u16* hp = hbase + (gp0 + n) * C;
    const u16* wu = wbase + (n + 1) * C;
    const u16* wv = wbase + n * C;
    f32x4 aU = (f32x4){0.f, 0.f, 0.f, 0.f};
    f32x4 aV = (f32x4){0.f, 0.f, 0.f, 0.f};
    f32x4 aS = (f32x4){0.f, 0.f, 0.f, 0.f};
    f32x4 aT = (f32x4){0.f, 0.f, 0.f, 0.f};
#pragma unroll
    for (int ks = 0; ks < KS; ++ks) {
      const bf16x8 av  = *(const bf16x8*)(ha + ks * 32);
      const bf16x8 avp = *(const bf16x8*)(hp + ks * 32);
      const bf16x8 bu  = *(const bf16x8*)(wu + ks * 32);
      const bf16x8 bv  = *(const bf16x8*)(wv + ks * 32);
      aU = __builtin_amdgcn_mfma_f32_16x16x32_bf16(av,  bu,      aU, 0, 0, 0);
      aV = __builtin_amdgcn_mfma_f32_16x16x32_bf16(av,  bv,      aV, 0, 0, 0);
      aS = __builtin_amdgcn_mfma_f32_16x16x32_bf16(av,  wsr[ks], aS, 0, 0, 0);
      aT = __builtin_amdgcn_mfma_f32_16x16x32_bf16(avp, wtr[ks], aT, 0, 0, 0);
    }
    sufRun -= aV;  // now = Sum_{j>n} V_j (global)
    const f32x4 val = runU + sufRun + aS + aT;
    runU += aU;
    const size_t rowbase = ((size_t)(b0 + quad * 4) * 80 + g0 + n) * O + o0 + m15;
#pragma unroll
    for (int t = 0; t < 4; t++) {
      float v = val[t] + bval;
      v = v > 0.f ? v : (__expf(v) - 1.f);
      hout[rowbase + (size_t)t * 80 * O] = f2b(v);
    }
  }
}

// ---------------------------------------------------------------------------
// Final layer (O=2), same decomposition, one block per (b, f), scalar dots.
// ---------------------------------------------------------------------------
__global__ __launch_bounds__(256)
void final_f(const u16* __restrict__ h3, const float* __restrict__ W4,
             const float* __restrict__ b4, float* __restrict__ out) {
  __shared__ u16 hf[2560], hp[2560];
  __shared__ float w4s[5248];
  __shared__ float uu[40][2], vv[40][2], ss[40][2], tt[40][2];
  const int bid = blockIdx.x, tid = threadIdx.x;
  const int b = bid >> 1, f = bid & 1;
  const u16* src_f = h3 + ((size_t)b * 80 + f * 40) * 64;
  const u16* src_p = h3 + ((size_t)b * 80 + (1 - f) * 40) * 64;
  for (int i = tid; i < 640; i += 256) {
    ((u16x4*)hf)[i] = ((const u16x4*)src_f)[i];
    ((u16x4*)hp)[i] = ((const u16x4*)src_p)[i];
  }
  for (int i = tid; i < 5248; i += 256) w4s[i] = W4[i];
  __syncthreads();
  for (int it = tid; it < 320; it += 256) {
    const int o = it & 1;
    const int part = (it >> 1) & 3;
    const int j = it >> 3;
    const int pos = part == 0 ? j + 1 : part == 1 ? j : part == 2 ? 0 : 40;
    const u16* hr = (part == 3 ? hp : hf) + j * 64;
    const float* wr = w4s + o * 2624 + pos * 64;
    float a = 0.f;
    for (int k = 0; k < 64; k++) a += b2f(hr[k]) * wr[k];
    if (part == 0) uu[j][o] = a;
    else if (part == 1) vv[j][o] = a;
    else if (part == 2) ss[j][o] = a;
    else tt[j][o] = a;
  }
  __syncthreads();
  if (tid < 80) {
    const int o = tid & 1, n = tid >> 1;
    float a = ss[n][o] + tt[n][o] + b4[o];
    for (int j = 0; j < n; j++) a += uu[j][o];
    for (int j = n + 1; j < 40; j++) a += vv[j][o];
    out[((size_t)b * 80 + f * 40 + n) * 2 + o] = a;
  }
}

// ---------------------------------------------------------------------------
// Small-workspace fallback path (round-0 proven gather-GEMM chain).
// ---------------------------------------------------------------------------
__global__ __launch_bounds__(256)
void cvt_x(const float* __restrict__ x, u16* __restrict__ xb) {
  const int i = blockIdx.x * 256 + threadIdx.x;
  if (i < 32768) {
    const f32x4 v = *(const f32x4*)(x + (size_t)i * 4);
    u16x4 o;
#pragma unroll
    for (int t = 0; t < 4; t++) o[t] = f2b(v[t]);
    *(u16x4*)(xb + (size_t)i * 4) = o;
  }
}

__global__ __launch_bounds__(256)
void final_k(const u16* __restrict__ h3, const float* __restrict__ W4,
             const float* __restrict__ b4, const int* __restrict__ gidx,
             float* __restrict__ out) {
  const int lane = threadIdx.x & 63;
  const int wave = threadIdx.x >> 6;
  const int r = blockIdx.x * 4 + wave;
  const int b = r / 80;
  const int n = r - b * 80;
  const int* ip = gidx + n * LSPIRAL;
  const float* w0 = W4 + lane;
  const float* w1 = W4 + 2624 + lane;
  const u16* hb = h3 + b * (NKPT * 64) + lane;
  float a0 = 0.f, a1 = 0.f;
  for (int l = 0; l < LSPIRAL; l++) {
    int J = ip[l];
    J = min(max(J, 0), NKPT - 1);
    const float hv = b2f(hb[J * 64]);
    a0 += hv * w0[l * 64];
    a1 += hv * w1[l * 64];
  }
#pragma unroll
  for (int off = 32; off > 0; off >>= 1) {
    a0 += __shfl_down(a0, off, 64);
    a1 += __shfl_down(a1, off, 64);
  }
  if (lane == 0) {
    out[r * 2 + 0] = a0 + b4[0];
    out[r * 2 + 1] = a1 + b4[1];
  }
}

template <int BM, int BN, int GATHER, int LOG2C, int OUTM, int BCVT, int LW>
__global__ __launch_bounds__(256)
void gemm_sp(const u16* __restrict__ A, const void* __restrict__ Wt,
             const int* __restrict__ gidx, float* __restrict__ P,
             u16* __restrict__ Out, const float* __restrict__ bias, int act,
             int N, int K, int itersTotal, int itersPerSplit) {
  constexpr int BK = 64;
  constexpr int WN = BN / 2;
  constexpr int TN = WN / 16;
  constexpr int IA = BM / 32;
  constexpr int IB = BN / 32;
  constexpr int CMASK = (1 << LOG2C) - 1;

  __shared__ u16 As[BM * BK];
  __shared__ u16 Bs[BN * BK];
  __shared__ int idx_s[GATHER ? NKPT * LW : 1];

  const int tid = threadIdx.x;
  const int lane = tid & 63;
  const int wave = tid >> 6;

  const int bm0 = blockIdx.x * BM;
  const int bn0 = blockIdx.y * BN;
  const int split = blockIdx.z;
  const int it0 = split * itersPerSplit;
  const int itEnd = min(itersTotal, it0 + itersPerSplit);
  const int l0 = GATHER ? ((it0 * BK) >> LOG2C) : 0;

  if (GATHER) {
    for (int t = tid; t < NKPT * LW; t += 256) {
      const int n = t / LW;
      const int w = t - n * LW;
      idx_s[t] = gidx[n * LSPIRAL + min(l0 + w, LSPIRAL - 1)];
    }
  }

  const int rIn = lane >> 3;
  const int koff = ((lane & 7) ^ rIn) * 8;

  int aBase[IA];
  const int* aIdxP[IA];
  const u16* aPtr[IA];
  u16* aDst[IA];
#pragma unroll
  for (int i = 0; i < IA; i++) {
    const int q = i * 4 + wave;
    const int r = bm0 + q * 8 + rIn;
    aDst[i] = As + q * 512;
    if (GATHER) {
      const int b = (r * 52429) >> 22;
      const int n = r - b * 80;
      aBase[i] = (b * NKPT) << LOG2C;
      aIdxP[i] = idx_s + n * LW;
    } else {
      aPtr[i] = A + (size_t)r * K + koff;
    }
  }
  const u16* bPtrH[IB];
  const float* bPtrF[IB];
  u16* bDst[IB];
#pragma unroll
  for (int i = 0; i < IB; i++) {
    const int q = i * 4 + wave;
    const int o = bn0 + q * 8 + rIn;
    bDst[i] = Bs + q * 512;
    if (BCVT) bPtrF[i] = (const float*)Wt + (size_t)o * K + koff;
    else bPtrH[i] = (const u16*)Wt + (size_t)o * K + koff;
  }

  f32x4 acc[4][TN];
#pragma unroll
  for (int i = 0; i < 4; i++)
#pragma unroll
    for (int j = 0; j < TN; j++) acc[i][j] = (f32x4){0.f, 0.f, 0.f, 0.f};

  const int wm = (wave >> 1) * 64;
  const int wn = (wave & 1) * WN;
  const int m15 = lane & 15;
  const int quad = lane >> 4;
  const int fko0 = ((0 + quad) ^ (lane & 7)) * 8;
  const int fko1 = ((4 + quad) ^ (lane & 7)) * 8;

  if (GATHER) __syncthreads();

  bf16x8 curA[IA], nxtA[IA];
  bf16x8 curB[IB], nxtB[IB];
  f32x8 curBF[BCVT ? IB : 1], nxtBF[BCVT ? IB : 1];

  auto loadA = [&](int it, bf16x8* dst) {
    const int k0 = it * BK;
    if (GATHER) {
      const int dl = (k0 >> LOG2C) - l0;
      const int cb = (k0 & CMASK) + koff;
#pragma unroll
      for (int i = 0; i < IA; i++) {
        int J = aIdxP[i][dl];
        J = min(max(J, 0), NKPT - 1);
        dst[i] = *(const bf16x8*)(A + aBase[i] + (J << LOG2C) + cb);
      }
    } else {
#pragma unroll
      for (int i = 0; i < IA; i++) dst[i] = *(const bf16x8*)(aPtr[i] + k0);
    }
  };
  auto loadBH = [&](int it, bf16x8* dst) {
    const int k0 = it * BK;
#pragma unroll
    for (int i = 0; i < IB; i++) dst[i] = *(const bf16x8*)(bPtrH[i] + k0);
  };
  auto loadBF = [&](int it, f32x8* dst) {
    const int k0 = it * BK;
#pragma unroll
    for (int i = 0; i < IB; i++) dst[i] = *(const f32x8*)(bPtrF[i] + k0);
  };

  loadA(it0, curA);
  if (BCVT) loadBF(it0, curBF); else loadBH(it0, curB);

  for (int it = it0; it < itEnd; ++it) {
    __syncthreads();
#pragma unroll
    for (int i = 0; i < IA; i++) *(bf16x8*)(aDst[i] + lane * 8) = curA[i];
    if (BCVT) {
#pragma unroll
      for (int i = 0; i < IB; i++) {
        bf16x8 w;
#pragma unroll
        for (int t = 0; t < 8; t++) w[t] = (bf16)curBF[i][t];
        *(bf16x8*)(bDst[i] + lane * 8) = w;
      }
    } else {
#pragma unroll
      for (int i = 0; i < IB; i++) *(bf16x8*)(bDst[i] + lane * 8) = curB[i];
    }
    __syncthreads();
    const bool more = (it + 1 < itEnd);
    if (more) {
      loadA(it + 1, nxtA);
      if (BCVT) loadBF(it + 1, nxtBF); else loadBH(it + 1, nxtB);
    }
#pragma unroll
    for (int kk = 0; kk < 2; kk++) {
      const int fko = kk ? fko1 : fko0;
      bf16x8 av[4], bv[TN];
#pragma unroll
      for (int i = 0; i < 4; i++)
        av[i] = *(const bf16x8*)(As + (wm + i * 16 + m15) * BK + fko);
#pragma unroll
      for (int j = 0; j < TN; j++)
        bv[j] = *(const bf16x8*)(Bs + (wn + j * 16 + m15) * BK + fko);
#pragma unroll
      for (int i = 0; i < 4; i++)
#pragma unroll
        for (int j = 0; j < TN; j++)
          acc[i][j] = __builtin_amdgcn_mfma_f32_16x16x32_bf16(av[i], bv[j], acc[i][j], 0, 0, 0);
    }
    if (more) {
#pragma unroll
      for (int i = 0; i < IA; i++) curA[i] = nxtA[i];
      if (BCVT) {
#pragma unroll
        for (int i = 0; i < IB; i++) curBF[i] = nxtBF[i];
      } else {
#pragma unroll
        for (int i = 0; i < IB; i++) curB[i] = nxtB[i];
      }
    }
  }

#pragma unroll
  for (int i = 0; i < 4; i++) {
    const int r = bm0 + wm + i * 16 + quad * 4;
#pragma unroll
    for (int j = 0; j < TN; j++) {
      const int c = bn0 + wn + j * 16 + m15;
      if (OUTM == 0) {
        const float bv = bias[c];
#pragma unroll
        for (int t = 0; t < 4; t++) {
          float v = acc[i][j][t] + bv;
          if (act) v = v > 0.f ? v : (__expf(v) - 1.f);
          Out[(size_t)(r + t) * N + c] = f2b(v);
        }
      } else {
#pragma unroll
        for (int t = 0; t < 4; t++)
          atomicAdd(P + (size_t)(r + t) * N + c, acc[i][j][t]);
      }
    }
  }
}

// ---------------------------------------------------------------------------
extern "C" void kernel_launch(void* const* d_in, const int* in_sizes, int n_in,
                              void* d_out, int out_size, void* d_ws, size_t ws_size,
                              hipStream_t stream) {
  const float* x  = (const float*)d_in[0];
  const float* W0 = (const float*)d_in[1];
  const float* b0 = (const float*)d_in[2];
  const float* W1 = (const float*)d_in[3];
  const float* b1 = (const float*)d_in[4];
  const float* W2 = (const float*)d_in[5];
  const float* b2 = (const float*)d_in[6];
  const float* W3 = (const float*)d_in[7];
  const float* b3 = (const float*)d_in[8];
  const float* W4 = (const float*)d_in[9];
  const float* b4 = (const float*)d_in[10];
  const int* idx = (const int*)d_in[11];
  float* out = (float*)d_out;

  char* ws = (char*)d_ws;
  u16* hA  = (u16*)(ws);                  // 5,242,880
  u16* hB  = (u16*)(ws + 5242880);        // 5,242,880
  u16* W1b = (u16*)(ws + 10485760);       // 5,373,952
  u16* W2b = (u16*)(ws + 15859712);       // 2,686,976
  u16* W3b = (u16*)(ws + 18546688);       //   671,744 -> ends 19,218,432

  if (ws_size >= (size_t)19218432) {
    // 5-dispatch fused path
    fuse0<<<448, 256, 0, stream>>>(x, W0, b0, W1, W2, W3, hA, W1b, W2b, W3b);
    layer_f<256, 10496><<<256, 256, 0, stream>>>(hA, W1b, b1, hB, 16, 256);
    layer_f<256, 10496><<<128, 256, 0, stream>>>(hB, W2b, b2, hA, 8, 128);
    layer_f<128, 5248><<<64, 256, 0, stream>>>(hA, W3b, b3, hB, 4, 64);
    final_f<<<256, 256, 0, stream>>>(hB, W4, b4, out);
  } else {
    // Small-ws fallback: gather-GEMM chain (round-0 proven), xb aliased to hB.
    u16* xb = hB;
    cvt_x<<<128, 256, 0, stream>>>(x, xb);
    gemm_sp<128, 64, 0, 0, 0, 1, 1><<<dim3(1, 320, 1), 256, 0, stream>>>(
        xb, W0, idx, nullptr, hA, b0, 0, 20480, 1024, 16, 16);
    gemm_sp<128, 128, 1, 8, 0, 1, 44><<<dim3(80, 2, 1), 256, 0, stream>>>(
        hA, W1, idx, nullptr, hB, b1, 1, 256, 10496, 164, 164);
    gemm_sp<128, 128, 1, 8, 0, 1, 44><<<dim3(80, 1, 1), 256, 0, stream>>>(
        hB, W2, idx, nullptr, hA, b2, 1, 128, 10496, 164, 164);
    gemm_sp<128, 64, 1, 7, 0, 1, 44><<<dim3(80, 1, 1), 256, 0, stream>>>(
        hA, W3, idx, nullptr, hB, b3, 1, 64, 5248, 82, 82);
    final_k<<<2560, 256, 0, stream>>>(hB, W4, b4, idx, out);
  }
}

// Round 5
// 287.709 us; speedup vs baseline: 3.0343x; 1.2119x over previous
//
#include <hip/hip_runtime.h>

typedef unsigned short u16;
typedef unsigned int u32;
typedef __bf16 bf16;
typedef __attribute__((ext_vector_type(8))) __bf16 bf16x8;
typedef __attribute__((ext_vector_type(4))) float f32x4;
typedef __attribute__((ext_vector_type(8))) float f32x8;
typedef __attribute__((ext_vector_type(4))) u16 u16x4;

#define NKPT 80
#define LSPIRAL 41

__device__ __forceinline__ float b2f(u16 v) { return __uint_as_float(((u32)v) << 16); }
__device__ __forceinline__ u16 f2b(float f) {
  u32 u = __float_as_uint(f);
  return (u16)((u + 0x7FFFu + ((u >> 16) & 1u)) >> 16);
}

// ---------------------------------------------------------------------------
// Weight f32->bf16 conversion, flat f32x4 index over W1|W2|W3.
// ---------------------------------------------------------------------------
#define CVT_TOTAL 1091584
__device__ __forceinline__ void cvt_range(int i, const float* __restrict__ W1,
    const float* __restrict__ W2, const float* __restrict__ W3,
    u16* __restrict__ W1b, u16* __restrict__ W2b, u16* __restrict__ W3b) {
  const float* src; u16* dst; int off;
  if (i < 671744)       { src = W1; dst = W1b; off = 0; }
  else if (i < 1007616) { src = W2; dst = W2b; off = 671744; }
  else                  { src = W3; dst = W3b; off = 1007616; }
  const int j = i - off;
  const f32x4 v = *(const f32x4*)(src + (size_t)j * 4);
  u16x4 o;
#pragma unroll
  for (int t = 0; t < 4; t++) o[t] = f2b(v[t]);
  *(u16x4*)(dst + (size_t)j * 4) = o;
}

// ---------------------------------------------------------------------------
// L0 tile (verified): M=128, BN=64 at bn0, K=1024, fp32 in, bf16 out + bias.
// ---------------------------------------------------------------------------
__device__ void dev_l0_tile(int bn0, const float* __restrict__ x,
                            const float* __restrict__ W0,
                            const float* __restrict__ b0,
                            u16* __restrict__ Out, u16* As, u16* Bs) {
  const int tid = threadIdx.x, lane = tid & 63, wave = tid >> 6;
  const int rIn = lane >> 3;
  const int koff = ((lane & 7) ^ rIn) * 8;
  const float* aP[4]; u16* aD[4];
  const float* bP[2]; u16* bD[2];
#pragma unroll
  for (int i = 0; i < 4; i++) {
    const int q = i * 4 + wave;
    aP[i] = x + (size_t)(q * 8 + rIn) * 1024 + koff;
    aD[i] = As + q * 512;
  }
#pragma unroll
  for (int i = 0; i < 2; i++) {
    const int q = i * 4 + wave;
    bP[i] = W0 + (size_t)(bn0 + q * 8 + rIn) * 1024 + koff;
    bD[i] = Bs + q * 512;
  }
  f32x4 acc[4][2];
#pragma unroll
  for (int i = 0; i < 4; i++)
#pragma unroll
    for (int j = 0; j < 2; j++) acc[i][j] = (f32x4){0.f, 0.f, 0.f, 0.f};

  const int wm = (wave >> 1) * 64, wn = (wave & 1) * 32;
  const int m15 = lane & 15, quad = lane >> 4;
  const int fko0 = ((0 + quad) ^ (lane & 7)) * 8;
  const int fko1 = ((4 + quad) ^ (lane & 7)) * 8;

  bf16x8 curA[4], nxtA[4], curB[2], nxtB[2];
  auto ldA = [&](int k0, bf16x8* d) {
#pragma unroll
    for (int i = 0; i < 4; i++) {
      const f32x8 v = *(const f32x8*)(aP[i] + k0);
      bf16x8 w;
#pragma unroll
      for (int t = 0; t < 8; t++) w[t] = (bf16)v[t];
      d[i] = w;
    }
  };
  auto ldB = [&](int k0, bf16x8* d) {
#pragma unroll
    for (int i = 0; i < 2; i++) {
      const f32x8 v = *(const f32x8*)(bP[i] + k0);
      bf16x8 w;
#pragma unroll
      for (int t = 0; t < 8; t++) w[t] = (bf16)v[t];
      d[i] = w;
    }
  };
  ldA(0, curA); ldB(0, curB);

  for (int it = 0; it < 16; ++it) {
    __syncthreads();
#pragma unroll
    for (int i = 0; i < 4; i++) *(bf16x8*)(aD[i] + lane * 8) = curA[i];
#pragma unroll
    for (int i = 0; i < 2; i++) *(bf16x8*)(bD[i] + lane * 8) = curB[i];
    __syncthreads();
    const bool more = (it + 1 < 16);
    if (more) { ldA((it + 1) * 64, nxtA); ldB((it + 1) * 64, nxtB); }
#pragma unroll
    for (int kk = 0; kk < 2; kk++) {
      const int fko = kk ? fko1 : fko0;
      bf16x8 av[4], bv[2];
#pragma unroll
      for (int i = 0; i < 4; i++)
        av[i] = *(const bf16x8*)(As + (wm + i * 16 + m15) * 64 + fko);
#pragma unroll
      for (int j = 0; j < 2; j++)
        bv[j] = *(const bf16x8*)(Bs + (wn + j * 16 + m15) * 64 + fko);
#pragma unroll
      for (int i = 0; i < 4; i++)
#pragma unroll
        for (int j = 0; j < 2; j++)
          acc[i][j] = __builtin_amdgcn_mfma_f32_16x16x32_bf16(av[i], bv[j], acc[i][j], 0, 0, 0);
    }
    if (more) {
#pragma unroll
      for (int i = 0; i < 4; i++) curA[i] = nxtA[i];
#pragma unroll
      for (int i = 0; i < 2; i++) curB[i] = nxtB[i];
    }
  }
#pragma unroll
  for (int i = 0; i < 4; i++) {
    const int r = wm + i * 16 + quad * 4;
#pragma unroll
    for (int j = 0; j < 2; j++) {
      const int c = bn0 + wn + j * 16 + m15;
      const float bv = b0[c];
#pragma unroll
      for (int t = 0; t < 4; t++)
        Out[(size_t)(r + t) * 20480 + c] = f2b(acc[i][j][t] + bv);
    }
  }
}

// Fused dispatch 1: blocks 0..319 do L0 tiles; blocks 320..447 do weight cvt.
__global__ __launch_bounds__(256)
void fuse0(const float* __restrict__ x, const float* __restrict__ W0,
           const float* __restrict__ b0, const float* __restrict__ W1,
           const float* __restrict__ W2, const float* __restrict__ W3,
           u16* __restrict__ h0, u16* __restrict__ W1b,
           u16* __restrict__ W2b, u16* __restrict__ W3b) {
  const int bid = blockIdx.x;
  if (bid < 320) {
    __shared__ u16 As[8192];
    __shared__ u16 Bs[8192];
    dev_l0_tile(bid * 64, x, W0, b0, h0, As, Bs);
  } else {
    for (int i = (bid - 320) * 256 + threadIdx.x; i < CVT_TOTAL; i += 128 * 256)
      cvt_range(i, W1, W2, W3, W1b, W2b, W3b);
  }
}

// ---------------------------------------------------------------------------
// Fused spiral layer, single compute pass, 8 waves (512 thr), 5 nodes/wave.
// Block = (b-chunk 16, frame f, o-chunk 16). Per node n (frame-local):
//   out_n = Sum_{j<n} U_j h_j + Sum_{j>n} V_j h_j + S h_n + T h_p(n)
// U_j = W[:,(j+1)C], V_j = W[:,jC], S = W[:,0], T = W[:,40C].
// Per node compute ONCE: aU = U_n h_n, aV = V_n h_n, aST = S h_n + T h_p
// (cached in regs). LDS-exchange per-wave totals -> prefix/suffix bases;
// finish scan purely in registers. Fragment layouts as verified (m89/m91).
// ---------------------------------------------------------------------------
template <int C, int LDW>
__global__ __launch_bounds__(512, 2)
void layer_s(const u16* __restrict__ hin, const u16* __restrict__ Wb,
             const float* __restrict__ bias, u16* __restrict__ hout,
             int nOC, int O) {
  constexpr int KS = C / 32;
  const int bid = blockIdx.x;
  const int b8 = bid / (2 * nOC);
  const int rest = bid - b8 * (2 * nOC);
  const int f = rest / nOC;
  const int oc = rest - f * nOC;
  const int b0 = b8 * 16;
  const int o0 = oc * 16;

  const int tid = threadIdx.x;
  const int lane = tid & 63;
  const int wave = tid >> 6;   // 0..7
  const int m15 = lane & 15;
  const int quad = lane >> 4;

  __shared__ float xch[4096];  // [wave][lane][8]: totU 0..3, totV 4..7 (16 KB)

  const u16* hbase = hin + (size_t)(b0 + m15) * (80 * C) + quad * 8;
  const u16* wbase = Wb + (size_t)(o0 + m15) * LDW + quad * 8;

  const int g0 = f * 40;
  const int gp0 = (1 - f) * 40;
  const int n0 = wave * 5;

  // Node-invariant S/T weight fragments.
  bf16x8 wsr[KS], wtr[KS];
#pragma unroll
  for (int ks = 0; ks < KS; ++ks) {
    wsr[ks] = *(const bf16x8*)(wbase + ks * 32);
    wtr[ks] = *(const bf16x8*)(wbase + 40 * C + ks * 32);
  }

  f32x4 aU[5], aV[5], aST[5];
#pragma unroll
  for (int i = 0; i < 5; ++i) {
    const int n = n0 + i;
    const u16* ha = hbase + (g0 + n) * C;
    const u16* hp = hbase + (gp0 + n) * C;
    const u16* wu = wbase + (n + 1) * C;
    const u16* wv = wbase + n * C;
    f32x4 u  = (f32x4){0.f, 0.f, 0.f, 0.f};
    f32x4 v  = (f32x4){0.f, 0.f, 0.f, 0.f};
    f32x4 st = (f32x4){0.f, 0.f, 0.f, 0.f};
#pragma unroll
    for (int ks = 0; ks < KS; ++ks) {
      const bf16x8 av  = *(const bf16x8*)(ha + ks * 32);
      const bf16x8 avp = *(const bf16x8*)(hp + ks * 32);
      const bf16x8 bu  = *(const bf16x8*)(wu + ks * 32);
      const bf16x8 bv  = *(const bf16x8*)(wv + ks * 32);
      u  = __builtin_amdgcn_mfma_f32_16x16x32_bf16(av,  bu,      u,  0, 0, 0);
      v  = __builtin_amdgcn_mfma_f32_16x16x32_bf16(av,  bv,      v,  0, 0, 0);
      st = __builtin_amdgcn_mfma_f32_16x16x32_bf16(av,  wsr[ks], st, 0, 0, 0);
      st = __builtin_amdgcn_mfma_f32_16x16x32_bf16(avp, wtr[ks], st, 0, 0, 0);
    }
    aU[i] = u; aV[i] = v; aST[i] = st;
  }

  f32x4 totU = aU[0] + aU[1] + aU[2] + aU[3] + aU[4];
  f32x4 totV = aV[0] + aV[1] + aV[2] + aV[3] + aV[4];

  // Exchange per-wave totals.
  {
    float* p = xch + wave * 512 + lane * 8;
#pragma unroll
    for (int t = 0; t < 4; t++) { p[t] = totU[t]; p[4 + t] = totV[t]; }
  }
  __syncthreads();
  f32x4 preU = (f32x4){0.f, 0.f, 0.f, 0.f};
  f32x4 sufV = (f32x4){0.f, 0.f, 0.f, 0.f};
#pragma unroll
  for (int w = 0; w < 8; ++w) {
    const float* p = xch + w * 512 + lane * 8;
    if (w < wave) {
#pragma unroll
      for (int t = 0; t < 4; t++) preU[t] += p[t];
    } else if (w > wave) {
#pragma unroll
      for (int t = 0; t < 4; t++) sufV[t] += p[4 + t];
    }
  }

  // Finish: register-only prefix/suffix scan + bias + ELU + store.
  const float bval = bias[o0 + m15];
  f32x4 runU = preU;
  f32x4 sufRun = sufV + totV;
#pragma unroll
  for (int i = 0; i < 5; ++i) {
    const int n = n0 + i;
    sufRun -= aV[i];
    const f32x4 val = runU + sufRun + aST[i];
    runU += aU[i];
    const size_t rowbase = ((size_t)(b0 + quad * 4) * 80 + g0 + n) * O + o0 + m15;
#pragma unroll
    for (int t = 0; t < 4; t++) {
      float vv = val[t] + bval;
      vv = vv > 0.f ? vv : (__expf(vv) - 1.f);
      hout[rowbase + (size_t)t * 80 * O] = f2b(vv);
    }
  }
}

// ---------------------------------------------------------------------------
// Final layer (O=2), one block per (b, f), scalar dots (verified round 4).
// ---------------------------------------------------------------------------
__global__ __launch_bounds__(256)
void final_f(const u16* __restrict__ h3, const float* __restrict__ W4,
             const float* __restrict__ b4, float* __restrict__ out) {
  __shared__ u16 hf[2560], hp[2560];
  __shared__ float w4s[5248];
  __shared__ float uu[40][2], vv[40][2], ss[40][2], tt[40][2];
  const int bid = blockIdx.x, tid = threadIdx.x;
  const int b = bid >> 1, f = bid & 1;
  const u16* src_f = h3 + ((size_t)b * 80 + f * 40) * 64;
  const u16* src_p = h3 + ((size_t)b * 80 + (1 - f) * 40) * 64;
  for (int i = tid; i < 640; i += 256) {
    ((u16x4*)hf)[i] = ((const u16x4*)src_f)[i];
    ((u16x4*)hp)[i] = ((const u16x4*)src_p)[i];
  }
  for (int i = tid; i < 5248; i += 256) w4s[i] = W4[i];
  __syncthreads();
  for (int it = tid; it < 320; it += 256) {
    const int o = it & 1;
    const int part = (it >> 1) & 3;
    const int j = it >> 3;
    const int pos = part == 0 ? j + 1 : part == 1 ? j : part == 2 ? 0 : 40;
    const u16* hr = (part == 3 ? hp : hf) + j * 64;
    const float* wr = w4s + o * 2624 + pos * 64;
    float a = 0.f;
    for (int k = 0; k < 64; k++) a += b2f(hr[k]) * wr[k];
    if (part == 0) uu[j][o] = a;
    else if (part == 1) vv[j][o] = a;
    else if (part == 2) ss[j][o] = a;
    else tt[j][o] = a;
  }
  __syncthreads();
  if (tid < 80) {
    const int o = tid & 1, n = tid >> 1;
    float a = ss[n][o] + tt[n][o] + b4[o];
    for (int j = 0; j < n; j++) a += uu[j][o];
    for (int j = n + 1; j < 40; j++) a += vv[j][o];
    out[((size_t)b * 80 + f * 40 + n) * 2 + o] = a;
  }
}

// ---------------------------------------------------------------------------
// Small-workspace fallback path (round-0 proven gather-GEMM chain).
// ---------------------------------------------------------------------------
__global__ __launch_bounds__(256)
void cvt_x(const float* __restrict__ x, u16* __restrict__ xb) {
  const int i = blockIdx.x * 256 + threadIdx.x;
  if (i < 32768) {
    const f32x4 v = *(const f32x4*)(x + (size_t)i * 4);
    u16x4 o;
#pragma unroll
    for (int t = 0; t < 4; t++) o[t] = f2b(v[t]);
    *(u16x4*)(xb + (size_t)i * 4) = o;
  }
}

__global__ __launch_bounds__(256)
void final_k(const u16* __restrict__ h3, const float* __restrict__ W4,
             const float* __restrict__ b4, const int* __restrict__ gidx,
             float* __restrict__ out) {
  const int lane = threadIdx.x & 63;
  const int wave = threadIdx.x >> 6;
  const int r = blockIdx.x * 4 + wave;
  const int b = r / 80;
  const int n = r - b * 80;
  const int* ip = gidx + n * LSPIRAL;
  const float* w0 = W4 + lane;
  const float* w1 = W4 + 2624 + lane;
  const u16* hb = h3 + b * (NKPT * 64) + lane;
  float a0 = 0.f, a1 = 0.f;
  for (int l = 0; l < LSPIRAL; l++) {
    int J = ip[l];
    J = min(max(J, 0), NKPT - 1);
    const float hv = b2f(hb[J * 64]);
    a0 += hv * w0[l * 64];
    a1 += hv * w1[l * 64];
  }
#pragma unroll
  for (int off = 32; off > 0; off >>= 1) {
    a0 += __shfl_down(a0, off, 64);
    a1 += __shfl_down(a1, off, 64);
  }
  if (lane == 0) {
    out[r * 2 + 0] = a0 + b4[0];
    out[r * 2 + 1] = a1 + b4[1];
  }
}

template <int BM, int BN, int GATHER, int LOG2C, int OUTM, int BCVT, int LW>
__global__ __launch_bounds__(256)
void gemm_sp(const u16* __restrict__ A, const void* __restrict__ Wt,
             const int* __restrict__ gidx, float* __restrict__ P,
             u16* __restrict__ Out, const float* __restrict__ bias, int act,
             int N, int K, int itersTotal, int itersPerSplit) {
  constexpr int BK = 64;
  constexpr int WN = BN / 2;
  constexpr int TN = WN / 16;
  constexpr int IA = BM / 32;
  constexpr int IB = BN / 32;
  constexpr int CMASK = (1 << LOG2C) - 1;

  __shared__ u16 As[BM * BK];
  __shared__ u16 Bs[BN * BK];
  __shared__ int idx_s[GATHER ? NKPT * LW : 1];

  const int tid = threadIdx.x;
  const int lane = tid & 63;
  const int wave = tid >> 6;

  const int bm0 = blockIdx.x * BM;
  const int bn0 = blockIdx.y * BN;
  const int split = blockIdx.z;
  const int it0 = split * itersPerSplit;
  const int itEnd = min(itersTotal, it0 + itersPerSplit);
  const int l0 = GATHER ? ((it0 * BK) >> LOG2C) : 0;

  if (GATHER) {
    for (int t = tid; t < NKPT * LW; t += 256) {
      const int n = t / LW;
      const int w = t - n * LW;
      idx_s[t] = gidx[n * LSPIRAL + min(l0 + w, LSPIRAL - 1)];
    }
  }

  const int rIn = lane >> 3;
  const int koff = ((lane & 7) ^ rIn) * 8;

  int aBase[IA];
  const int* aIdxP[IA];
  const u16* aPtr[IA];
  u16* aDst[IA];
#pragma unroll
  for (int i = 0; i < IA; i++) {
    const int q = i * 4 + wave;
    const int r = bm0 + q * 8 + rIn;
    aDst[i] = As + q * 512;
    if (GATHER) {
      const int b = (r * 52429) >> 22;
      const int n = r - b * 80;
      aBase[i] = (b * NKPT) << LOG2C;
      aIdxP[i] = idx_s + n * LW;
    } else {
      aPtr[i] = A + (size_t)r * K + koff;
    }
  }
  const u16* bPtrH[IB];
  const float* bPtrF[IB];
  u16* bDst[IB];
#pragma unroll
  for (int i = 0; i < IB; i++) {
    const int q = i * 4 + wave;
    const int o = bn0 + q * 8 + rIn;
    bDst[i] = Bs + q * 512;
    if (BCVT) bPtrF[i] = (const float*)Wt + (size_t)o * K + koff;
    else bPtrH[i] = (const u16*)Wt + (size_t)o * K + koff;
  }

  f32x4 acc[4][TN];
#pragma unroll
  for (int i = 0; i < 4; i++)
#pragma unroll
    for (int j = 0; j < TN; j++) acc[i][j] = (f32x4){0.f, 0.f, 0.f, 0.f};

  const int wm = (wave >> 1) * 64;
  const int wn = (wave & 1) * WN;
  const int m15 = lane & 15;
  const int quad = lane >> 4;
  const int fko0 = ((0 + quad) ^ (lane & 7)) * 8;
  const int fko1 = ((4 + quad) ^ (lane & 7)) * 8;

  if (GATHER) __syncthreads();

  bf16x8 curA[IA], nxtA[IA];
  bf16x8 curB[IB], nxtB[IB];
  f32x8 curBF[BCVT ? IB : 1], nxtBF[BCVT ? IB : 1];

  auto loadA = [&](int it, bf16x8* dst) {
    const int k0 = it * BK;
    if (GATHER) {
      const int dl = (k0 >> LOG2C) - l0;
      const int cb = (k0 & CMASK) + koff;
#pragma unroll
      for (int i = 0; i < IA; i++) {
        int J = aIdxP[i][dl];
        J = min(max(J, 0), NKPT - 1);
        dst[i] = *(const bf16x8*)(A + aBase[i] + (J << LOG2C) + cb);
      }
    } else {
#pragma unroll
      for (int i = 0; i < IA; i++) dst[i] = *(const bf16x8*)(aPtr[i] + k0);
    }
  };
  auto loadBH = [&](int it, bf16x8* dst) {
    const int k0 = it * BK;
#pragma unroll
    for (int i = 0; i < IB; i++) dst[i] = *(const bf16x8*)(bPtrH[i] + k0);
  };
  auto loadBF = [&](int it, f32x8* dst) {
    const int k0 = it * BK;
#pragma unroll
    for (int i = 0; i < IB; i++) dst[i] = *(const f32x8*)(bPtrF[i] + k0);
  };

  loadA(it0, curA);
  if (BCVT) loadBF(it0, curBF); else loadBH(it0, curB);

  for (int it = it0; it < itEnd; ++it) {
    __syncthreads();
#pragma unroll
    for (int i = 0; i < IA; i++) *(bf16x8*)(aDst[i] + lane * 8) = curA[i];
    if (BCVT) {
#pragma unroll
      for (int i = 0; i < IB; i++) {
        bf16x8 w;
#pragma unroll
        for (int t = 0; t < 8; t++) w[t] = (bf16)curBF[i][t];
        *(bf16x8*)(bDst[i] + lane * 8) = w;
      }
    } else {
#pragma unroll
      for (int i = 0; i < IB; i++) *(bf16x8*)(bDst[i] + lane * 8) = curB[i];
    }
    __syncthreads();
    const bool more = (it + 1 < itEnd);
    if (more) {
      loadA(it + 1, nxtA);
      if (BCVT) loadBF(it + 1, nxtBF); else loadBH(it + 1, nxtB);
    }
#pragma unroll
    for (int kk = 0; kk < 2; kk++) {
      const int fko = kk ? fko1 : fko0;
      bf16x8 av[4], bv[TN];
#pragma unroll
      for (int i = 0; i < 4; i++)
        av[i] = *(const bf16x8*)(As + (wm + i * 16 + m15) * BK + fko);
#pragma unroll
      for (int j = 0; j < TN; j++)
        bv[j] = *(const bf16x8*)(Bs + (wn + j * 16 + m15) * BK + fko);
#pragma unroll
      for (int i = 0; i < 4; i++)
#pragma unroll
        for (int j = 0; j < TN; j++)
          acc[i][j] = __builtin_amdgcn_mfma_f32_16x16x32_bf16(av[i], bv[j], acc[i][j], 0, 0, 0);
    }
    if (more) {
#pragma unroll
      for (int i = 0; i < IA; i++) curA[i] = nxtA[i];
      if (BCVT) {
#pragma unroll
        for (int i = 0; i < IB; i++) curBF[i] = nxtBF[i];
      } else {
#pragma unroll
        for (int i = 0; i < IB; i++) curB[i] = nxtB[i];
      }
    }
  }

#pragma unroll
  for (int i = 0; i < 4; i++) {
    const int r = bm0 + wm + i * 16 + quad * 4;
#pragma unroll
    for (int j = 0; j < TN; j++) {
      const int c = bn0 + wn + j * 16 + m15;
      if (OUTM == 0) {
        const float bv = bias[c];
#pragma unroll
        for (int t = 0; t < 4; t++) {
          float v = acc[i][j][t] + bv;
          if (act) v = v > 0.f ? v : (__expf(v) - 1.f);
          Out[(size_t)(r + t) * N + c] = f2b(v);
        }
      } else {
#pragma unroll
        for (int t = 0; t < 4; t++)
          atomicAdd(P + (size_t)(r + t) * N + c, acc[i][j][t]);
      }
    }
  }
}

// ---------------------------------------------------------------------------
extern "C" void kernel_launch(void* const* d_in, const int* in_sizes, int n_in,
                              void* d_out, int out_size, void* d_ws, size_t ws_size,
                              hipStream_t stream) {
  const float* x  = (const float*)d_in[0];
  const float* W0 = (const float*)d_in[1];
  const float* b0 = (const float*)d_in[2];
  const float* W1 = (const float*)d_in[3];
  const float* b1 = (const float*)d_in[4];
  const float* W2 = (const float*)d_in[5];
  const float* b2 = (const float*)d_in[6];
  const float* W3 = (const float*)d_in[7];
  const float* b3 = (const float*)d_in[8];
  const float* W4 = (const float*)d_in[9];
  const float* b4 = (const float*)d_in[10];
  const int* idx = (const int*)d_in[11];
  float* out = (float*)d_out;

  char* ws = (char*)d_ws;
  u16* hA  = (u16*)(ws);                  // 5,242,880
  u16* hB  = (u16*)(ws + 5242880);        // 5,242,880
  u16* W1b = (u16*)(ws + 10485760);       // 5,373,952
  u16* W2b = (u16*)(ws + 15859712);       // 2,686,976
  u16* W3b = (u16*)(ws + 18546688);       //   671,744 -> ends 19,218,432

  if (ws_size >= (size_t)19218432) {
    // 5-dispatch fused path
    fuse0<<<448, 256, 0, stream>>>(x, W0, b0, W1, W2, W3, hA, W1b, W2b, W3b);
    layer_s<256, 10496><<<256, 512, 0, stream>>>(hA, W1b, b1, hB, 16, 256);
    layer_s<256, 10496><<<128, 512, 0, stream>>>(hB, W2b, b2, hA, 8, 128);
    layer_s<128, 5248><<<64, 512, 0, stream>>>(hA, W3b, b3, hB, 4, 64);
    final_f<<<256, 256, 0, stream>>>(hB, W4, b4, out);
  } else {
    // Small-ws fallback: gather-GEMM chain (round-0 proven), xb aliased to hB.
    u16* xb = hB;
    cvt_x<<<128, 256, 0, stream>>>(x, xb);
    gemm_sp<128, 64, 0, 0, 0, 1, 1><<<dim3(1, 320, 1), 256, 0, stream>>>(
        xb, W0, idx, nullptr, hA, b0, 0, 20480, 1024, 16, 16);
    gemm_sp<128, 128, 1, 8, 0, 1, 44><<<dim3(80, 2, 1), 256, 0, stream>>>(
        hA, W1, idx, nullptr, hB, b1, 1, 256, 10496, 164, 164);
    gemm_sp<128, 128, 1, 8, 0, 1, 44><<<dim3(80, 1, 1), 256, 0, stream>>>(
        hB, W2, idx, nullptr, hA, b2, 1, 128, 10496, 164, 164);
    gemm_sp<128, 64, 1, 7, 0, 1, 44><<<dim3(80, 1, 1), 256, 0, stream>>>(
        hA, W3, idx, nullptr, hB, b3, 1, 64, 5248, 82, 82);
    final_k<<<2560, 256, 0, stream>>>(hB, W4, b4, idx, out);
  }
}